// Round 5
// baseline (105.884 us; speedup 1.0000x reference)
//
#include <hip/hip_runtime.h>
#include <math.h>

#define NATOMS    128
#define NSEG      7875     // segments: i in [0,124], j in [i+2,126]
#define M_TRIU    8126     // (n*n-n)/2 - 2
#define PADLEN    8128     // M_TRIU + 2
#define OUT_PER_B 16256    // 2 * PADLEN
#define BLOCK     1024
#define CHUNK     8        // segments per thread (1024*8 >= 7875)

struct F3 { float x, y, z; };
__device__ __forceinline__ F3 f3sub(F3 a, F3 b) { return {a.x - b.x, a.y - b.y, a.z - b.z}; }
__device__ __forceinline__ F3 f3neg(F3 a) { return {-a.x, -a.y, -a.z}; }
__device__ __forceinline__ F3 f3cross(F3 a, F3 b) {
    return {a.y * b.z - a.z * b.y, a.z * b.x - a.x * b.z, a.x * b.y - a.y * b.x};
}
__device__ __forceinline__ float f3dot(F3 a, F3 b) { return a.x * b.x + a.y * b.y + a.z * b.z; }
__device__ __forceinline__ F3 f3norm(F3 a) {
    float rn = __builtin_amdgcn_rsqf(f3dot(a, a));   // single v_rsq_f32
    return {a.x * rn, a.y * rn, a.z * rn};
}
__device__ __forceinline__ float clip1(float x) { return fminf(1.0f, fmaxf(-1.0f, x)); }

// Branchless asin, A&S 4.4.46 (|err| ~ 2e-8); single v_sqrt_f32.
__device__ __forceinline__ float fast_asin(float x) {
    float a = fabsf(x);
    float p = -0.0012624911f;
    p = fmaf(p, a,  0.0066700901f);
    p = fmaf(p, a, -0.0170881256f);
    p = fmaf(p, a,  0.0308918810f);
    p = fmaf(p, a, -0.0501743046f);
    p = fmaf(p, a,  0.0889789874f);
    p = fmaf(p, a, -0.2145988016f);
    p = fmaf(p, a,  1.5707963050f);
    float r = 1.57079632679f - __builtin_amdgcn_sqrtf(1.0f - a) * p;
    return copysignf(r, x);
}

__device__ __forceinline__ int seg_row_base(int i) { return 125 * i - (i * (i - 1)) / 2; }
__device__ __forceinline__ int pair_row_base(int a) { return (a * (255 - a)) / 2; }

// One block per batch. Phase A walks chains of consecutive-j segments so that
// d0/d2 carry over and n3 = -n1_prev (exact), 3 LDS reads/segment, and the
// triangular-index inversion runs once per CHUNK with predicated fixups.
// LDS: coords 1.5K + swr 31.5K + triu 32.5K ~= 65.6 KB; 2 blocks/CU.
__global__ __launch_bounds__(BLOCK, 8) void writhe_fused(
    const float* __restrict__ xyz,       // (B, 128, 3)
    const int*   __restrict__ sortv,     // (16256,)
    float*       __restrict__ out)       // (B, 16256)
{
    __shared__ float sx[NATOMS], sy[NATOMS], sz[NATOMS];
    __shared__ float swr[NSEG];
    __shared__ float triu[M_TRIU];

    const int b = blockIdx.x;
    const int t = threadIdx.x;

    if (t < 3 * NATOMS) {
        float v = xyz[(size_t)b * (3 * NATOMS) + t];
        int a = t / 3, c = t - 3 * a;
        if (c == 0) sx[a] = v; else if (c == 1) sy[a] = v; else sz[a] = v;
    }
    __syncthreads();

    // ---------- Phase A: chained writhe ----------
    const int s0 = t * CHUNK;
    if (s0 < NSEG) {
        // invert s0 -> (i,j) once; predicated fixups (no divergent loops)
        int i = (int)((251.0f - __builtin_amdgcn_sqrtf(63001.0f - 8.0f * (float)s0)) * 0.5f);
        i = max(i, 0);
        i += (seg_row_base(i + 1) <= s0);
        i += (seg_row_base(i + 1) <= s0);
        i -= (seg_row_base(i) > s0);
        i -= (seg_row_base(i) > s0);
        int j = s0 - seg_row_base(i) + i + 2;

        F3 pi, pi1, e, pj, d0, d2, n3;
        bool fresh = true;
        const int send = min(s0 + CHUNK, NSEG);
        for (int s = s0; s < send; ++s) {
            if (fresh) {
                pi  = {sx[i],     sy[i],     sz[i]};
                pi1 = {sx[i + 1], sy[i + 1], sz[i + 1]};
                e   = f3sub(pi1, pi);
                pj  = {sx[j], sy[j], sz[j]};
                d0  = f3norm(f3sub(pj, pi));
                d2  = f3norm(f3sub(pj, pi1));
                n3  = f3norm(f3cross(d2, d0));
                fresh = false;
            }
            F3 pj1 = {sx[j + 1], sy[j + 1], sz[j + 1]};
            F3 d1 = f3norm(f3sub(pj1, pi));
            F3 d3 = f3norm(f3sub(pj1, pi1));

            F3 n0 = f3norm(f3cross(d0, d1));
            F3 n1 = f3norm(f3cross(d1, d3));
            F3 n2 = f3norm(f3cross(d3, d2));

            F3 axial = f3cross(f3sub(pj1, pj), e);
            float sd = f3dot(axial, d0);
            float sgn = (sd > 0.0f) ? 1.0f : ((sd < 0.0f) ? -1.0f : 0.0f);

            float c0 = clip1(f3dot(n0, n1));
            float c1 = clip1(f3dot(n1, n2));
            float c2 = clip1(f3dot(n2, n3));
            float c3 = clip1(f3dot(n3, n0));

            float omega = fast_asin(c0) + fast_asin(c1) + fast_asin(c2) + fast_asin(c3);
            swr[s] = omega * sgn * 0.15915494309189535f;  // / (2*pi)

            // advance chain: (i,j) -> (i,j+1)
            d0 = d1; d2 = d3; n3 = f3neg(n1); pj = pj1;
            ++j;
            if (j > 126) { ++i; j = i + 2; fresh = true; }
        }
    }
    __syncthreads();

    // ---------- Phase B: gather-form Laplacian ----------
    for (int m = t; m < M_TRIU; m += BLOCK) {
        int q = m + 1;
        int a = (int)((255.0f - __builtin_amdgcn_sqrtf(65025.0f - 8.0f * (float)q)) * 0.5f);
        a = max(a, 0);
        a += (pair_row_base(a + 1) <= q);
        a += (pair_row_base(a + 1) <= q);
        a -= (pair_row_base(a) > q);
        a -= (pair_row_base(a) > q);
        int bb = a + 1 + (q - pair_row_base(a));

        float sum = 0.0f;
        #pragma unroll
        for (int di = -1; di <= 0; ++di) {
            #pragma unroll
            for (int dj = -1; dj <= 0; ++dj) {
                int i = a + di, j = bb + dj;
                bool valid = (i >= 0) && (i <= 124) && (j >= i + 2) && (j <= 126);
                int s = valid ? (seg_row_base(i) + (j - i - 2)) : 0;
                float v = swr[s];
                sum += valid ? v : 0.0f;
            }
        }
        triu[m] = sum;
    }
    __syncthreads();

    // ---------- Phase C: permuted output ----------
    float* ob = out + (size_t)b * OUT_PER_B;
    for (int k = t; k < OUT_PER_B; k += BLOCK) {
        int v = sortv[k];
        int p = (v >= PADLEN) ? (v - PADLEN) : v;
        float val = (p == 0 || p == PADLEN - 1) ? 0.0f : triu[p - 1];
        ob[k] = val;
    }
}

extern "C" void kernel_launch(void* const* d_in, const int* in_sizes, int n_in,
                              void* d_out, int out_size, void* d_ws, size_t ws_size,
                              hipStream_t stream) {
    const float* xyz   = (const float*)d_in[0];
    const int*   sortv = (const int*)d_in[3];
    float*       out   = (float*)d_out;

    int B = in_sizes[0] / (NATOMS * 3);   // 512 for the reference shapes
    writhe_fused<<<B, BLOCK, 0, stream>>>(xyz, sortv, out);
}

// Round 6
// 105.066 us; speedup vs baseline: 1.0078x; 1.0078x over previous
//
#include <hip/hip_runtime.h>
#include <math.h>

#define NATOMS    128
#define NSEG      7875     // segments: i in [0,124], j in [i+2,126]
#define M_TRIU    8126     // (n*n-n)/2 - 2
#define PADLEN    8128     // M_TRIU + 2
#define OUT_PER_B 16256    // 2 * PADLEN
#define BLOCK     1024

struct F3 { float x, y, z; };
__device__ __forceinline__ F3 f3sub(F3 a, F3 b) { return {a.x - b.x, a.y - b.y, a.z - b.z}; }
__device__ __forceinline__ F3 f3cross(F3 a, F3 b) {
    return {a.y * b.z - a.z * b.y, a.z * b.x - a.x * b.z, a.x * b.y - a.y * b.x};
}
__device__ __forceinline__ float f3dot(F3 a, F3 b) { return a.x * b.x + a.y * b.y + a.z * b.z; }
__device__ __forceinline__ float clip1(float x) { return fminf(1.0f, fmaxf(-1.0f, x)); }

// Branchless asin, A&S 4.4.46 (|err| ~ 2e-8); single v_sqrt_f32.
__device__ __forceinline__ float fast_asin(float x) {
    float a = fabsf(x);
    float p = -0.0012624911f;
    p = fmaf(p, a,  0.0066700901f);
    p = fmaf(p, a, -0.0170881256f);
    p = fmaf(p, a,  0.0308918810f);
    p = fmaf(p, a, -0.0501743046f);
    p = fmaf(p, a,  0.0889789874f);
    p = fmaf(p, a, -0.2145988016f);
    p = fmaf(p, a,  1.5707963050f);
    float r = 1.57079632679f - __builtin_amdgcn_sqrtf(1.0f - a) * p;
    return copysignf(r, x);
}

__device__ __forceinline__ int seg_row_base(int i) { return 125 * i - (i * (i - 1)) / 2; }
__device__ __forceinline__ int pair_row_base(int a) { return (a * (255 - a)) / 2; }

// One block per batch. Flat stride-1 segment loop (conflict-free LDS, no
// divergence). Normalization-free writhe: unit(d_a x d_b) is invariant to
// the scale of d_a/d_b, so the 4 displacement normalizations are dropped and
// each angle uses one rsq of the product of squared norms (8 transcendentals
// per segment instead of 12, ~40 fewer VALU ops).
// LDS: coords 1.5K + swr 31.5K + triu 32.5K ~= 65.6 KB; 2 blocks/CU.
__global__ __launch_bounds__(BLOCK, 8) void writhe_fused(
    const float* __restrict__ xyz,       // (B, 128, 3)
    const int*   __restrict__ sortv,     // (16256,)
    float*       __restrict__ out)       // (B, 16256)
{
    __shared__ float sx[NATOMS], sy[NATOMS], sz[NATOMS];
    __shared__ float swr[NSEG];
    __shared__ float triu[M_TRIU];

    const int b = blockIdx.x;
    const int t = threadIdx.x;

    if (t < 3 * NATOMS) {
        float v = xyz[(size_t)b * (3 * NATOMS) + t];
        int a = t / 3, c = t - 3 * a;
        if (c == 0) sx[a] = v; else if (c == 1) sy[a] = v; else sz[a] = v;
    }
    __syncthreads();

    // ---------- Phase A: writhe per segment ----------
    for (int s = t; s < NSEG; s += BLOCK) {
        // invert s -> (i,j), predicated fixups (no divergent loops)
        int i = (int)((251.0f - __builtin_amdgcn_sqrtf(63001.0f - 8.0f * (float)s)) * 0.5f);
        i = max(i, 0);
        i += (seg_row_base(i + 1) <= s);
        i += (seg_row_base(i + 1) <= s);
        i -= (seg_row_base(i) > s);
        i -= (seg_row_base(i) > s);
        int j = s - seg_row_base(i) + i + 2;

        F3 p0 = {sx[i],     sy[i],     sz[i]};
        F3 p1 = {sx[i + 1], sy[i + 1], sz[i + 1]};
        F3 p2 = {sx[j],     sy[j],     sz[j]};
        F3 p3 = {sx[j + 1], sy[j + 1], sz[j + 1]};

        // Unnormalized displacements (normalization cancels in unit(cross)).
        F3 u0 = f3sub(p2, p0);
        F3 u1 = f3sub(p3, p0);
        F3 u2 = f3sub(p2, p1);
        F3 u3 = f3sub(p3, p1);

        F3 n0 = f3cross(u0, u1);
        F3 n1 = f3cross(u1, u3);
        F3 n2 = f3cross(u3, u2);
        F3 n3 = f3cross(u2, u0);

        float q0 = f3dot(n0, n0);
        float q1 = f3dot(n1, n1);
        float q2 = f3dot(n2, n2);
        float q3 = f3dot(n3, n3);

        float c0 = clip1(f3dot(n0, n1) * __builtin_amdgcn_rsqf(q0 * q1));
        float c1 = clip1(f3dot(n1, n2) * __builtin_amdgcn_rsqf(q1 * q2));
        float c2 = clip1(f3dot(n2, n3) * __builtin_amdgcn_rsqf(q2 * q3));
        float c3 = clip1(f3dot(n3, n0) * __builtin_amdgcn_rsqf(q3 * q0));

        F3 axial = f3cross(f3sub(p3, p2), f3sub(p1, p0));
        float sd = f3dot(axial, u0);      // sign(axial . d0) == sign(axial . u0)
        float sgn = (sd > 0.0f) ? 1.0f : ((sd < 0.0f) ? -1.0f : 0.0f);

        float omega = fast_asin(c0) + fast_asin(c1) + fast_asin(c2) + fast_asin(c3);
        swr[s] = omega * sgn * 0.15915494309189535f;  // / (2*pi)
    }
    __syncthreads();

    // ---------- Phase B: gather-form Laplacian ----------
    for (int m = t; m < M_TRIU; m += BLOCK) {
        int q = m + 1;
        int a = (int)((255.0f - __builtin_amdgcn_sqrtf(65025.0f - 8.0f * (float)q)) * 0.5f);
        a = max(a, 0);
        a += (pair_row_base(a + 1) <= q);
        a += (pair_row_base(a + 1) <= q);
        a -= (pair_row_base(a) > q);
        a -= (pair_row_base(a) > q);
        int bb = a + 1 + (q - pair_row_base(a));

        float sum = 0.0f;
        #pragma unroll
        for (int di = -1; di <= 0; ++di) {
            #pragma unroll
            for (int dj = -1; dj <= 0; ++dj) {
                int i = a + di, j = bb + dj;
                bool valid = (i >= 0) && (i <= 124) && (j >= i + 2) && (j <= 126);
                int s = valid ? (seg_row_base(i) + (j - i - 2)) : 0;
                float v = swr[s];
                sum += valid ? v : 0.0f;
            }
        }
        triu[m] = sum;
    }
    __syncthreads();

    // ---------- Phase C: permuted output ----------
    float* ob = out + (size_t)b * OUT_PER_B;
    for (int k = t; k < OUT_PER_B; k += BLOCK) {
        int v = sortv[k];
        int p = (v >= PADLEN) ? (v - PADLEN) : v;
        float val = (p == 0 || p == PADLEN - 1) ? 0.0f : triu[p - 1];
        ob[k] = val;
    }
}

extern "C" void kernel_launch(void* const* d_in, const int* in_sizes, int n_in,
                              void* d_out, int out_size, void* d_ws, size_t ws_size,
                              hipStream_t stream) {
    const float* xyz   = (const float*)d_in[0];
    const int*   sortv = (const int*)d_in[3];
    float*       out   = (float*)d_out;

    int B = in_sizes[0] / (NATOMS * 3);   // 512 for the reference shapes
    writhe_fused<<<B, BLOCK, 0, stream>>>(xyz, sortv, out);
}